// Round 16
// baseline (57.748 us; speedup 1.0000x reference)
//
#include <hip/hip_runtime.h>
#include <hip/hip_bf16.h>

// ShuffleNet fused block-MLP, MI355X (gfx950).  R16 = R15 + CU-AFFINE np.
// Decode np = b&15: block->CU round-robins mod 256, so all WGs resident on a
// CU share ONE np -> per-CU weight working set = 33 KB ~= L1 (was 16x33KB).
// Weight loads become L1 hits; only streaming xT loads go to L2/L3.
// Everything else identical to R15 (passed, absmax 9.77e-4).
// x:(8192,1024) f32; w1:(16,256,64); b1:(4096); w2:(16,64,256); b2:(1024); y f32.
//   h[b,n,o] = sum_i x[b,n*64+i]*w1[n,o,i];  shuffled j = o*16+n
//   g = gelu(h+b1);  y[b,np*64+o'] = sum_K g[b,np*256+K]*w2'[np,o',K] + b2
// Register-local shuffle via pi-permuted w2 pack:
//   pi(k) = 32*(k>>5) + 16*((k>>2)&1) + 4*((k>>3)&3) + (k&3); GEMM2 A-frag of
//   slice s = this lane's own packed GEMM1 outputs for n=2s,2s+1.
// xT frag (rt,n,ks): lane l elem e = bf16(x[rt*16+(l&15)][n*64+ks*32+(l>>4)*8+e])
//   at xT[((rt*16+n)*2+ks)*512 + l*8 + e]  (1KB/wave contiguous).

typedef __attribute__((ext_vector_type(8))) short  short8;   // 8 bf16 = 4 VGPR
typedef __attribute__((ext_vector_type(4))) short  short4v;
typedef __attribute__((ext_vector_type(4))) float  floatx4;

__device__ __forceinline__ short f2bf(float f) {
  union { __hip_bfloat16 h; short s; } u;
  u.h = __float2bfloat16(f);
  return u.s;
}
__device__ __forceinline__ float bf2f(short s) {
  union { float f; unsigned u; } uu;
  uu.u = ((unsigned)(unsigned short)s) << 16;
  return uu.f;
}
__device__ __forceinline__ int pk16(float a, float b) {
  return (int)(unsigned short)f2bf(a) | ((int)(unsigned short)f2bf(b) << 16);
}

// gelu(v) ~= v * sigmoid(1.5957691*(v + 0.044715 v^3)), exp2-folded (abs<5e-4)
__device__ __forceinline__ float gelu_f(float v) {
  float m = v * v;
  float c = fmaf(-0.1029375f, m, -2.3020807f);
  float z = v * c;
  float e = __builtin_amdgcn_exp2f(z);
  return v * __builtin_amdgcn_rcpf(1.0f + e);
}

// ---- pack kernel: w1 frags | w2 frags (pi-permuted) | b1 frags (bf16) ----
__global__ void pack_k(const float* __restrict__ w1, const float* __restrict__ w2,
                       const float* __restrict__ b1, short* __restrict__ w1p,
                       short* __restrict__ w2p, short* __restrict__ b1p) {
  const int t = blockIdx.x * blockDim.x + threadIdx.x;  // 160*512 = 81920
  const int lane = t & 63;
  const int lhi = lane >> 4;
  if (t < 32768) {  // w1 frag (n,np,ks): lane l elem e = w1[n][np*16+(l&15)][ks*32+lhi*8+e]
    const int ks = (t >> 6) & 1, np = (t >> 7) & 15, n = (t >> 11) & 15;
    const float* src = w1 + ((size_t)(n * 256 + np * 16 + (lane & 15)) * 64 + ks * 32 + lhi * 8);
    short8 f;
#pragma unroll
    for (int e = 0; e < 8; ++e) f[e] = f2bf(src[e]);
    *(short8*)(w1p + (size_t)t * 8) = f;
  } else if (t < 65536) {  // w2 frag (np,s,ot), pi-permuted k
    const int t2 = t - 32768;
    const int ot = (t2 >> 6) & 3, s = (t2 >> 8) & 7, np = (t2 >> 11) & 15;
    const int op = ot * 16 + (lane & 15);
    short8 f;
#pragma unroll
    for (int e = 0; e < 8; ++e) {
      const int Kc = 32 * s + 16 * ((e >> 2) & 1) + 4 * lhi + (e & 3);
      const int n = Kc >> 4, ohi = Kc & 15;
      f[e] = f2bf(w2[(size_t)(np * 64 + op) * 256 + ohi * 16 + n]);
    }
    *(short8*)(w2p + (size_t)t2 * 8) = f;
  } else {  // b1 frag (n,np): lane l reg r = bf16(b1[(np*16+lhi*4+r)*16+n])
    const int t3 = t - 65536;  // 16384
    const int np = (t3 >> 6) & 15, n = (t3 >> 10) & 15;
    short4v b;
#pragma unroll
    for (int r = 0; r < 4; ++r) b[r] = f2bf(b1[(np * 16 + lhi * 4 + r) * 16 + n]);
    *(short4v*)(b1p + (size_t)((n * 16 + np) * 64 + lane) * 4) = b;
  }
}

// ---- pack_x: x (f32, row-major) -> xT (bf16, B-frag order). Streaming. ----
// 2048 WGs x 256 thr; wave = (rt = b>>2, n = (b&3)*4 + wv). x read once (NT).
__global__ __launch_bounds__(256, 4) void pack_x(
    const float* __restrict__ x, short* __restrict__ xT) {
  const int tid = threadIdx.x;
  const int wv = tid >> 6, lane = tid & 63;
  const int l15 = lane & 15, lhi = lane >> 4;
  const int rt = blockIdx.x >> 2;
  const int n  = (blockIdx.x & 3) * 4 + wv;

  const float* px = x + (size_t)(rt * 16 + l15) * 1024 + n * 64 + lhi * 8;
#pragma unroll
  for (int ks = 0; ks < 2; ++ks) {
    floatx4 a = __builtin_nontemporal_load((const floatx4*)(px + ks * 32));
    floatx4 b = __builtin_nontemporal_load((const floatx4*)(px + ks * 32 + 4));
    short8 f;
#pragma unroll
    for (int e = 0; e < 4; ++e) { f[e] = f2bf(a[e]); f[e + 4] = f2bf(b[e]); }
    *(short8*)(xT + ((size_t)(rt * 16 + n) * 2 + ks) * 512 + lane * 8) = f;
  }
}

// ---- fused: 2048 WGs x 256 thr; WG = (np = b&15, rtg = b>>4); k2-shaped ----
// wave wv handles rowtile rt = rtg*4 + wv with the WG's single np.
__global__ __launch_bounds__(256, 4) void fused_k(
    const short* __restrict__ xT, const short* __restrict__ w1p,
    const short* __restrict__ w2p, const short* __restrict__ b1p,
    const float* __restrict__ b2, float* __restrict__ y) {
  const int tid = threadIdx.x;
  const int wv = tid >> 6, lane = tid & 63;
  const int l15 = lane & 15, lhi = lane >> 4;
  const int np  = blockIdx.x & 15;             // CU-affine: (b+256k)&15 invariant
  const int rt  = (blockIdx.x >> 4) * 4 + wv;  // 0..511

  floatx4 c0 = {0.f,0.f,0.f,0.f}, c1 = {0.f,0.f,0.f,0.f};
  floatx4 c2 = {0.f,0.f,0.f,0.f}, c3 = {0.f,0.f,0.f,0.f};

#pragma unroll
  for (int s = 0; s < 8; ++s) {
    union { int i[4]; short8 v; } af;

#pragma unroll
    for (int half = 0; half < 2; ++half) {
      const int n = 2 * s + half;
      short8 xf0 = *(const short8*)(xT + ((size_t)(rt * 16 + n) * 2 + 0) * 512 + lane * 8);
      short8 xf1 = *(const short8*)(xT + ((size_t)(rt * 16 + n) * 2 + 1) * 512 + lane * 8);
      short8 wf0 = *(const short8*)(w1p + (size_t)(((n * 16 + np) * 2 + 0) * 64 + lane) * 8);
      short8 wf1 = *(const short8*)(w1p + (size_t)(((n * 16 + np) * 2 + 1) * 64 + lane) * 8);
      short4v bv = *(const short4v*)(b1p + (size_t)((n * 16 + np) * 64 + lane) * 4);
      floatx4 acc = {0.f, 0.f, 0.f, 0.f};
      acc = __builtin_amdgcn_mfma_f32_16x16x32_bf16(wf0, xf0, acc, 0, 0, 0);
      acc = __builtin_amdgcn_mfma_f32_16x16x32_bf16(wf1, xf1, acc, 0, 0, 0);
      af.i[2 * half + 0] = pk16(gelu_f(acc[0] + bf2f(bv[0])), gelu_f(acc[1] + bf2f(bv[1])));
      af.i[2 * half + 1] = pk16(gelu_f(acc[2] + bf2f(bv[2])), gelu_f(acc[3] + bf2f(bv[3])));
    }

    // GEMM2 slice s: A-frag is this lane's own registers (pi-fold)
    const size_t wb = (size_t)((np * 8 + s) * 4) * 64 * 8;
    short8 bf0  = *(const short8*)(w2p + wb + (size_t)(0 * 64 + lane) * 8);
    short8 bf1  = *(const short8*)(w2p + wb + (size_t)(1 * 64 + lane) * 8);
    short8 bf2v = *(const short8*)(w2p + wb + (size_t)(2 * 64 + lane) * 8);
    short8 bf3  = *(const short8*)(w2p + wb + (size_t)(3 * 64 + lane) * 8);
    c0 = __builtin_amdgcn_mfma_f32_16x16x32_bf16(af.v, bf0,  c0, 0, 0, 0);
    c1 = __builtin_amdgcn_mfma_f32_16x16x32_bf16(af.v, bf1,  c1, 0, 0, 0);
    c2 = __builtin_amdgcn_mfma_f32_16x16x32_bf16(af.v, bf2v, c2, 0, 0, 0);
    c3 = __builtin_amdgcn_mfma_f32_16x16x32_bf16(af.v, bf3,  c3, 0, 0, 0);
  }

  // y store (NT): col = np*64 + ot*16 + l15, rows rt*16 + lhi*4 + r
  floatx4 cc[4] = {c0, c1, c2, c3};
#pragma unroll
  for (int ot = 0; ot < 4; ++ot) {
    const int col = np * 64 + ot * 16 + l15;
    const float bb = b2[col];
    float* py = y + (size_t)(rt * 16 + lhi * 4) * 1024 + col;
#pragma unroll
    for (int r = 0; r < 4; ++r)
      __builtin_nontemporal_store(cc[ot][r] + bb, py + (size_t)r * 1024);
  }
}

extern "C" void kernel_launch(void* const* d_in, const int* in_sizes, int n_in,
                              void* d_out, int out_size, void* d_ws, size_t ws_size,
                              hipStream_t stream) {
  const float* x  = (const float*)d_in[0];
  const float* w1 = (const float*)d_in[1];
  const float* b1 = (const float*)d_in[2];
  const float* w2 = (const float*)d_in[3];
  const float* b2 = (const float*)d_in[4];
  float* y = (float*)d_out;

  short* w1p = (short*)d_ws;               // 512 KB
  short* w2p = w1p + 16 * 256 * 64;        // 512 KB
  short* b1p = w2p + 16 * 256 * 64;        // 128 KB
  short* xT  = b1p + 16 * 16 * 64 * 4;     // 16 MB (bf16 fragment-order x)

  pack_k<<<160, 512, 0, stream>>>(w1, w2, b1, w1p, w2p, b1p);
  pack_x<<<2048, 256, 0, stream>>>(x, xT);
  fused_k<<<2048, 256, 0, stream>>>(xT, w1p, w2p, b1p, b2, y);
}

// Round 17
// 46.686 us; speedup vs baseline: 1.2369x; 1.2369x over previous
//
#include <hip/hip_runtime.h>
#include <hip/hip_bf16.h>

// ShuffleNet fused block-MLP, MI355X (gfx950).  R17: register-blocked 2rt x 2np.
// Model from R4..R16 data: dur ~ total vector-memory LINE-REQUESTS (~130/cyc
// chip ceiling); hits vs misses secondary. So reuse must live in regs/LDS:
//  - wave owns 2 rowtiles x 2 np (4 tasks): each weight frag feeds 2 rt,
//    each bf feeds 2 MFMA, each xf LDS-read feeds 2 np  -> global requests
//    cut ~2.2x (13.6M -> ~6.3M lines).
//  - WG (4 waves = np-octet, oct = b&1 -> XCD-affine weight set 576 KB in L2)
//    stages 32 x-rows to LDS once (coalesced, ONE barrier). No pack_x.
// Math identical to R11/R13/R15/R16 (passed, absmax 9.77e-4): pi-permuted w2
// pack makes GEMM2's A-frag the lane's own GEMM1 outputs (register-local
// shuffle); pi(k) = 32*(k>>5) + 16*((k>>2)&1) + 4*((k>>3)&3) + (k&3).

typedef __attribute__((ext_vector_type(8))) short  short8;   // 8 bf16 = 4 VGPR
typedef __attribute__((ext_vector_type(4))) short  short4v;
typedef __attribute__((ext_vector_type(4))) float  floatx4;

#define XP 1032   // LDS row pitch in shorts (516 dw = 4 mod 32 -> bank rotation)

__device__ __forceinline__ short f2bf(float f) {
  union { __hip_bfloat16 h; short s; } u;
  u.h = __float2bfloat16(f);
  return u.s;
}
__device__ __forceinline__ float bf2f(short s) {
  union { float f; unsigned u; } uu;
  uu.u = ((unsigned)(unsigned short)s) << 16;
  return uu.f;
}
__device__ __forceinline__ int pk16(float a, float b) {
  return (int)(unsigned short)f2bf(a) | ((int)(unsigned short)f2bf(b) << 16);
}

// gelu(v) ~= v * sigmoid(1.5957691*(v + 0.044715 v^3)), exp2-folded (abs<5e-4)
__device__ __forceinline__ float gelu_f(float v) {
  float m = v * v;
  float c = fmaf(-0.1029375f, m, -2.3020807f);
  float z = v * c;
  float e = __builtin_amdgcn_exp2f(z);
  return v * __builtin_amdgcn_rcpf(1.0f + e);
}

// ---- pack kernel: w1 frags | w2 frags (pi-permuted) | b1 frags (bf16) ----
// (unchanged since R11; proven)
__global__ void pack_k(const float* __restrict__ w1, const float* __restrict__ w2,
                       const float* __restrict__ b1, short* __restrict__ w1p,
                       short* __restrict__ w2p, short* __restrict__ b1p) {
  const int t = blockIdx.x * blockDim.x + threadIdx.x;  // 160*512 = 81920
  const int lane = t & 63;
  const int lhi = lane >> 4;
  if (t < 32768) {  // w1 frag (n,np,ks): lane l elem e = w1[n][np*16+(l&15)][ks*32+lhi*8+e]
    const int ks = (t >> 6) & 1, np = (t >> 7) & 15, n = (t >> 11) & 15;
    const float* src = w1 + ((size_t)(n * 256 + np * 16 + (lane & 15)) * 64 + ks * 32 + lhi * 8);
    short8 f;
#pragma unroll
    for (int e = 0; e < 8; ++e) f[e] = f2bf(src[e]);
    *(short8*)(w1p + (size_t)t * 8) = f;
  } else if (t < 65536) {  // w2 frag (np,s,ot), pi-permuted k
    const int t2 = t - 32768;
    const int ot = (t2 >> 6) & 3, s = (t2 >> 8) & 7, np = (t2 >> 11) & 15;
    const int op = ot * 16 + (lane & 15);
    short8 f;
#pragma unroll
    for (int e = 0; e < 8; ++e) {
      const int Kc = 32 * s + 16 * ((e >> 2) & 1) + 4 * lhi + (e & 3);
      const int n = Kc >> 4, ohi = Kc & 15;
      f[e] = f2bf(w2[(size_t)(np * 64 + op) * 256 + ohi * 16 + n]);
    }
    *(short8*)(w2p + (size_t)t2 * 8) = f;
  } else {  // b1 frag (n,np): lane l reg r = bf16(b1[(np*16+lhi*4+r)*16+n])
    const int t3 = t - 65536;  // 16384
    const int np = (t3 >> 6) & 15, n = (t3 >> 10) & 15;
    short4v b;
#pragma unroll
    for (int r = 0; r < 4; ++r) b[r] = f2bf(b1[(np * 16 + lhi * 4 + r) * 16 + n]);
    *(short4v*)(b1p + (size_t)((n * 16 + np) * 64 + lane) * 4) = b;
  }
}

// ---- fused: 512 WGs x 256 thr; WG = (oct = b&1, rtp = b>>1) ----
// wave wv: np-pair {oct*8+wv*2, +1}; processes rowtiles rtp*2 and rtp*2+1.
__global__ __launch_bounds__(256, 2) void fused_k(
    const float* __restrict__ x, const short* __restrict__ w1p,
    const short* __restrict__ w2p, const short* __restrict__ b1p,
    const float* __restrict__ b2, float* __restrict__ y) {
  __shared__ __align__(16) short xs[32 * XP];   // 66 KB: 32 staged x rows (bf16)

  const int tid = threadIdx.x;
  const int wv = tid >> 6, lane = tid & 63;
  const int l15 = lane & 15, lhi = lane >> 4;
  const int oct = blockIdx.x & 1;       // == (b&7)&1 -> XCD-affine np-octet
  const int rtp = blockIdx.x >> 1;      // 0..255 rowtile-pair
  const int np0 = oct * 8 + wv * 2;

  // ---- stage: 32 rows x 1024 f32 -> bf16 LDS (coalesced; NT: x read once) ----
#pragma unroll
  for (int j = 0; j < 16; ++j) {
    const int cid = j * 256 + tid;
    const int row = cid >> 7;           // 0..31
    const int ch  = cid & 127;          // 16B bf16 chunk within row
    const float* px = x + (size_t)(rtp * 32 + row) * 1024 + ch * 8;
    floatx4 a = __builtin_nontemporal_load((const floatx4*)px);
    floatx4 b = __builtin_nontemporal_load((const floatx4*)(px + 4));
    short8 f;
#pragma unroll
    for (int e = 0; e < 4; ++e) { f[e] = f2bf(a[e]); f[e + 4] = f2bf(b[e]); }
    *(short8*)(&xs[row * XP + ch * 8]) = f;
  }
  __syncthreads();   // the only barrier

  floatx4 c[2][2][4];   // [npi][rt][ot] — all indices compile-time constant
#pragma unroll
  for (int i = 0; i < 2; ++i)
#pragma unroll
    for (int r = 0; r < 2; ++r)
#pragma unroll
      for (int o = 0; o < 4; ++o) c[i][r][o] = (floatx4){0.f, 0.f, 0.f, 0.f};

#pragma unroll
  for (int s = 0; s < 8; ++s) {
    const int n0 = 2 * s, n1 = 2 * s + 1;

    // xf LDS reads — shared by both np of the pair (request-free reuse)
    short8 xf[2][2][2];   // [rt][nhalf][ks], static indices
#pragma unroll
    for (int r = 0; r < 2; ++r)
#pragma unroll
      for (int h = 0; h < 2; ++h)
#pragma unroll
        for (int ks = 0; ks < 2; ++ks)
          xf[r][h][ks] = *(const short8*)(
              &xs[(r * 16 + l15) * XP + (2 * s + h) * 64 + ks * 32 + lhi * 8]);

#pragma unroll
    for (int npi = 0; npi < 2; ++npi) {
      const int np = np0 + npi;
      // weight frags: each used for BOTH rowtiles (2x register reuse)
      short8 wf00 = *(const short8*)(w1p + (size_t)(((n0 * 16 + np) * 2 + 0) * 64 + lane) * 8);
      short8 wf01 = *(const short8*)(w1p + (size_t)(((n0 * 16 + np) * 2 + 1) * 64 + lane) * 8);
      short8 wf10 = *(const short8*)(w1p + (size_t)(((n1 * 16 + np) * 2 + 0) * 64 + lane) * 8);
      short8 wf11 = *(const short8*)(w1p + (size_t)(((n1 * 16 + np) * 2 + 1) * 64 + lane) * 8);
      short4v bv0 = *(const short4v*)(b1p + (size_t)((n0 * 16 + np) * 64 + lane) * 4);
      short4v bv1 = *(const short4v*)(b1p + (size_t)((n1 * 16 + np) * 64 + lane) * 4);

      // GEMM1 + gelu for both rowtiles -> af[rt]
      union { int i[4]; short8 v; } af[2];
#pragma unroll
      for (int r = 0; r < 2; ++r) {
        floatx4 a0 = {0.f, 0.f, 0.f, 0.f}, a1 = {0.f, 0.f, 0.f, 0.f};
        a0 = __builtin_amdgcn_mfma_f32_16x16x32_bf16(wf00, xf[r][0][0], a0, 0, 0, 0);
        a0 = __builtin_amdgcn_mfma_f32_16x16x32_bf16(wf01, xf[r][0][1], a0, 0, 0, 0);
        a1 = __builtin_amdgcn_mfma_f32_16x16x32_bf16(wf10, xf[r][1][0], a1, 0, 0, 0);
        a1 = __builtin_amdgcn_mfma_f32_16x16x32_bf16(wf11, xf[r][1][1], a1, 0, 0, 0);
        af[r].i[0] = pk16(gelu_f(a0[0] + bf2f(bv0[0])), gelu_f(a0[1] + bf2f(bv0[1])));
        af[r].i[1] = pk16(gelu_f(a0[2] + bf2f(bv0[2])), gelu_f(a0[3] + bf2f(bv0[3])));
        af[r].i[2] = pk16(gelu_f(a1[0] + bf2f(bv1[0])), gelu_f(a1[1] + bf2f(bv1[1])));
        af[r].i[3] = pk16(gelu_f(a1[2] + bf2f(bv1[2])), gelu_f(a1[3] + bf2f(bv1[3])));
      }

      // GEMM2 slice s: each bf frag feeds BOTH rowtiles (2x reuse)
      const size_t wb = (size_t)((np * 8 + s) * 4) * 64 * 8;
#pragma unroll
      for (int ot = 0; ot < 4; ++ot) {
        short8 bf = *(const short8*)(w2p + wb + (size_t)(ot * 64 + lane) * 8);
        c[npi][0][ot] = __builtin_amdgcn_mfma_f32_16x16x32_bf16(af[0].v, bf, c[npi][0][ot], 0, 0, 0);
        c[npi][1][ot] = __builtin_amdgcn_mfma_f32_16x16x32_bf16(af[1].v, bf, c[npi][1][ot], 0, 0, 0);
      }
    }
  }

  // ---- epilogue: y[rtp*32 + r*16 + lhi*4 + rr][np*64 + ot*16 + l15] ----
#pragma unroll
  for (int npi = 0; npi < 2; ++npi) {
    const int np = np0 + npi;
#pragma unroll
    for (int ot = 0; ot < 4; ++ot) {
      const int col = np * 64 + ot * 16 + l15;
      const float bb = b2[col];
#pragma unroll
      for (int r = 0; r < 2; ++r) {
        float* py = y + (size_t)(rtp * 32 + r * 16 + lhi * 4) * 1024 + col;
#pragma unroll
        for (int rr = 0; rr < 4; ++rr)
          __builtin_nontemporal_store(c[npi][r][ot][rr] + bb, py + (size_t)rr * 1024);
      }
    }
  }
}

extern "C" void kernel_launch(void* const* d_in, const int* in_sizes, int n_in,
                              void* d_out, int out_size, void* d_ws, size_t ws_size,
                              hipStream_t stream) {
  const float* x  = (const float*)d_in[0];
  const float* w1 = (const float*)d_in[1];
  const float* b1 = (const float*)d_in[2];
  const float* w2 = (const float*)d_in[3];
  const float* b2 = (const float*)d_in[4];
  float* y = (float*)d_out;

  short* w1p = (short*)d_ws;               // 512 KB
  short* w2p = w1p + 16 * 256 * 64;        // 512 KB
  short* b1p = w2p + 16 * 256 * 64;        // 128 KB

  pack_k<<<160, 512, 0, stream>>>(w1, w2, b1, w1p, w2p, b1p);
  fused_k<<<512, 256, 0, stream>>>(x, w1p, w2p, b1p, b2, y);
}